// Round 9
// baseline (148.069 us; speedup 1.0000x reference)
//
#include <hip/hip_runtime.h>
#include <hip/hip_bf16.h>
#include <math.h>

#define Bg   128
#define Nn   64
#define Tt   256
#define INF  320      // Nn + Tt
#define Hd   256
#define OUTD 128
#define Ee   2016     // Nn*(Nn-1)/2
#define TOTE (Bg*Ee)  // 258048
#define SCOLS 576     // padded 514 -> 9*64 so GEMM2 tiles exactly
#define MROWS 8192    // Bg*Nn

typedef __attribute__((ext_vector_type(8))) short bf16x8;
typedef __attribute__((ext_vector_type(4))) float f32x4;

static __device__ __forceinline__ ushort f2bf(float v) {
    __hip_bfloat16 h = __float2bfloat16(v);
    return *(ushort*)&h;
}

// ================= fused agg + weight-prep kernel =================
// Blocks [0, Bg*5): prefix-mean aggregation (LDS-tiled scan) -> bf16.
// Blocks [Bg*5, ...): weight swizzle into MFMA-fragment-linear order + ebias + red init.
//
// Swizzled B layout (per GEMM, reduction dim K, output dim N):
//   elem idx = ((((n0/64)*(K/32) + kw)*4 + ns)*64 + lane)*8 + j
//   maps to W[k][n] with n = (n0/64)*64 + ns*16 + (lane&15), k = kw*32 + (lane>>4)*8 + j
// so a wave's 64 lanes read 1024 contiguous bytes per (ns, kw) fragment.
#define CVT_N (INF * Hd)                  // 81920
#define PACK_N (Hd * SCOLS)               // 147456
#define AGG_BLKS (Bg * 5)

__global__ __launch_bounds__(256) void k_agg_prep(
        const float* __restrict__ topo, const float* __restrict__ temp,
        const float* __restrict__ Wg, const float* __restrict__ Wm,
        const float* __restrict__ Wv, const float* __restrict__ Ww,
        const float* __restrict__ bm, const float* __restrict__ bv,
        const float* __restrict__ bw,
        ushort* __restrict__ agg, ushort* __restrict__ WgbS,
        ushort* __restrict__ WcatS, float* __restrict__ ebias,
        unsigned* __restrict__ red) {
    __shared__ float T[64 * 65];
    const int bid = blockIdx.x;
    const int tid = threadIdx.x;

    if (bid < AGG_BLKS) {
        const int b = bid / 5, ft = bid - 5 * (bid / 5);
        const int row = tid >> 2, seg = tid & 3;
        const float* src = (ft == 0) ? (topo + (size_t)(b * Nn + row) * Nn)
                                     : (temp + (size_t)(b * Nn + row) * Tt + (ft - 1) * 64);
        #pragma unroll
        for (int i = 0; i < 4; ++i) {
            float4 v = *(const float4*)(src + seg * 16 + i * 4);
            float* d = &T[row * 65 + seg * 16 + i * 4];
            d[0] = v.x; d[1] = v.y; d[2] = v.z; d[3] = v.w;
        }
        __syncthreads();
        const int w = tid >> 6, lane = tid & 63;
        #pragma unroll
        for (int k = 0; k < 16; ++k) {
            int f = w * 16 + k;
            float x = T[lane * 65 + f];
            float incl = x;
            #pragma unroll
            for (int o = 1; o < 64; o <<= 1) {
                float t = __shfl_up(incl, o);
                if (lane >= o) incl += t;
            }
            float excl = incl - x;
            T[lane * 65 + f] = lane ? excl * __builtin_amdgcn_rcpf((float)lane) : 0.f;
        }
        __syncthreads();
        const int node = tid >> 2, f0 = (tid & 3) * 16;
        ushort tmp[16];
        #pragma unroll
        for (int i = 0; i < 16; ++i) tmp[i] = f2bf(T[node * 65 + f0 + i]);
        ushort* dst = agg + (size_t)(b * Nn + node) * INF + ft * 64 + f0;
        *(uint4*)dst = *(uint4*)tmp;
        *(uint4*)(dst + 8) = *(uint4*)(tmp + 8);
        return;
    }

    int idx = (bid - AGG_BLKS) * 256 + tid;
    if (idx == 0) { red[0] = 0u; red[1] = 0u; }
    if (idx < CVT_N) {
        // Wg swizzle: K=320 (10 windows), N=256 (4 tiles). Wg is [320][256] row-major.
        int j = idx & 7, lane = (idx >> 3) & 63, ns = (idx >> 9) & 3;
        int rem = idx >> 11;                  // 0..39
        int kw = rem % 10, t = rem / 10;
        int n = t * 64 + ns * 16 + (lane & 15);
        int k = kw * 32 + (lane >> 4) * 8 + j;
        WgbS[idx] = f2bf(Wg[k * Hd + n]);
        return;
    }
    idx -= CVT_N;
    if (idx < PACK_N) {
        // Wcat swizzle: K=256 (8 windows), N=576 (9 tiles). col n, reduction k.
        int j = idx & 7, lane = (idx >> 3) & 63, ns = (idx >> 9) & 3;
        int rem = idx >> 11;                  // 0..71
        int kw = rem % 8, t = rem / 8;
        int n = t * 64 + ns * 16 + (lane & 15);
        int k = kw * 32 + (lane >> 4) * 8 + j;
        float v = 0.f;
        if (n < 128)       v = Wm[k * 128 + n];
        else if (n < 256)  v = Wm[(256 + k) * 128 + (n - 128)];
        else if (n < 384)  v = Wv[k * 128 + (n - 256)];
        else if (n < 512)  v = Wv[(256 + k) * 128 + (n - 384)];
        else if (n == 512) v = Ww[k];
        else if (n == 513) v = Ww[256 + k];
        WcatS[idx] = f2bf(v);
        return;
    }
    idx -= PACK_N;
    if (idx >= SCOLS) return;
    float e = 0.f;
    if (idx < 128)                    e = bm[idx];
    else if (idx >= 256 && idx < 384) e = bv[idx - 256];
    else if (idx == 512)              e = bw[0];
    ebias[idx] = e;
}

// ================= barrier-free direct-VGPR MFMA GEMM =================
// 64x64 tile, 256 thr = 4 waves; wave w owns rows m0+w*16..+15. No LDS, no barriers.
// A: MxK bf16 row-major (per-lane global_load_dwordx4, 16 rows x 64B lines).
// Bsw: swizzled fragment-linear weights (see k_agg_prep).
// transC=0: C row-major (Cb bf16 w/ bias+relu, else Cf fp32).
// transC=1: Cf fp32 transposed (Cf[col][row], ld=MROWS), bias per col.
template<int K>
__global__ __launch_bounds__(256) void k_gemm_direct(const ushort* __restrict__ A,
                                                     const ushort* __restrict__ Bsw,
                                                     const float* __restrict__ bias,
                                                     ushort* __restrict__ Cb,
                                                     float* __restrict__ Cf,
                                                     int N, int relu, int transC) {
    const int tid = threadIdx.x;
    const int w = tid >> 6, lane = tid & 63;
    const int quad = lane >> 4, r16 = lane & 15;
    const int m0 = blockIdx.y * 64, n0 = blockIdx.x * 64;
    const ushort* arow = A + (size_t)(m0 + w * 16 + r16) * K + quad * 8;
    const ushort* bbase = Bsw + (size_t)blockIdx.x * (K / 32) * 2048 + lane * 8;
    f32x4 acc[4] = {};

    #pragma unroll 2
    for (int kw = 0; kw < K / 32; ++kw) {
        bf16x8 af = *(const bf16x8*)(arow + kw * 32);
        const ushort* bp = bbase + kw * 2048;
        bf16x8 b0 = *(const bf16x8*)(bp);
        bf16x8 b1 = *(const bf16x8*)(bp + 512);
        bf16x8 b2 = *(const bf16x8*)(bp + 1024);
        bf16x8 b3 = *(const bf16x8*)(bp + 1536);
        acc[0] = __builtin_amdgcn_mfma_f32_16x16x32_bf16(af, b0, acc[0], 0, 0, 0);
        acc[1] = __builtin_amdgcn_mfma_f32_16x16x32_bf16(af, b1, acc[1], 0, 0, 0);
        acc[2] = __builtin_amdgcn_mfma_f32_16x16x32_bf16(af, b2, acc[2], 0, 0, 0);
        acc[3] = __builtin_amdgcn_mfma_f32_16x16x32_bf16(af, b3, acc[3], 0, 0, 0);
    }

    const int row0 = m0 + w * 16 + quad * 4;
    #pragma unroll
    for (int ns = 0; ns < 4; ++ns) {
        f32x4 a = acc[ns];
        int col = n0 + ns * 16 + r16;
        float bb = bias ? bias[col] : 0.f;
        float vv[4];
        #pragma unroll
        for (int i = 0; i < 4; ++i) {
            float v = a[i] + bb;
            if (relu) v = fmaxf(v, 0.f);
            vv[i] = v;
        }
        if (transC) {
            *(float4*)(Cf + (size_t)col * MROWS + row0) = make_float4(vv[0], vv[1], vv[2], vv[3]);
        } else {
            #pragma unroll
            for (int i = 0; i < 4; ++i) {
                int row2 = row0 + i;
                if (Cb) Cb[(size_t)row2 * N + col] = f2bf(vv[i]);
                else    Cf[(size_t)row2 * N + col] = vv[i];
            }
        }
    }
}

// ================= fused edge kernel -> numer + denominator atomic =================
// 1280 blocks = 128 graphs x 10 group-pairs (4 groups of 16 nodes, g0<=g1).
static __device__ __forceinline__ float eterm(float pm, float qm, float pv, float qv) {
    float m = pm + qm;
    float x = pv + qv;
    float sp = fmaxf(x, 0.f) + __logf(1.f + __expf(-fabsf(x)));
    return m * m * __builtin_amdgcn_rcpf(sp + 1.01e-6f);
}

__global__ __launch_bounds__(256) void k_edge4(const float* __restrict__ ST,
                                               const float* __restrict__ gu,
                                               float* __restrict__ numer,
                                               unsigned* __restrict__ red) {
    __shared__ float L[4][16][132];
    __shared__ float sm[256];
    const int p = blockIdx.x % 10, b = blockIdx.x / 10;
    const int G0v[10] = {0,0,0,0,1,1,1,2,2,3};
    const int G1v[10] = {0,1,2,3,1,2,3,2,3,3};
    const int g0 = G0v[p], g1 = G1v[p];
    const int tid = threadIdx.x;

    #pragma unroll
    for (int rep = 0; rep < 8; ++rep) {
        int it = tid + 256 * rep;              // 0..2047
        int arr = it >> 9;                     // 0..3
        int c = (it >> 2) & 127, nq = it & 3;  // t-row, node-quad
        int g = (arr & 1) ? g1 : g0;
        float4 v = *(const float4*)&ST[(size_t)(arr * 128 + c) * MROWS + b * 64 + g * 16 + nq * 4];
        L[arr][nq * 4 + 0][c] = v.x;
        L[arr][nq * 4 + 1][c] = v.y;
        L[arr][nq * 4 + 2][c] = v.z;
        L[arr][nq * 4 + 3][c] = v.w;
    }
    __syncthreads();

    const int i = tid >> 4, j = tid & 15;
    float acc = 0.f;
    #pragma unroll 4
    for (int t = 0; t < 128; t += 4) {
        float4 mi = *(const float4*)&L[0][i][t];
        float4 mj = *(const float4*)&L[1][j][t];
        float4 vi = *(const float4*)&L[2][i][t];
        float4 vj = *(const float4*)&L[3][j][t];
        acc += eterm(mi.x, mj.x, vi.x, vj.x);
        acc += eterm(mi.y, mj.y, vi.y, vj.y);
        acc += eterm(mi.z, mj.z, vi.z, vj.z);
        acc += eterm(mi.w, mj.w, vi.w, vj.w);
    }

    const int ni = g0 * 16 + i, nj = g1 * 16 + j;
    float en = 0.f;
    if (ni < nj) {
        int e = b * Ee + (ni * (127 - ni)) / 2 + (nj - ni - 1);
        float se = __expf(acc * (-1.f / 256.f));   // exp(-0.5*acc/128)
        float wr = ST[(size_t)512 * MROWS + b * 64 + ni]
                 + ST[(size_t)513 * MROWS + b * 64 + nj];   // bw folded into row 512
        float w  = __builtin_amdgcn_rcpf(1.f + __expf(-wr));
        float g  = -__logf(-__logf(gu[e]));
        en = __expf((w + g) * 2.0f);               // exp(logit), logit <= ~36: safe
        numer[e] = se * en;
    }
    sm[tid] = en; __syncthreads();
    for (int s = 128; s; s >>= 1) {
        if (tid < s) sm[tid] += sm[tid + s];
        __syncthreads();
    }
    if (!tid) atomicAdd((float*)&red[1], sm[0]);
}

// ================= final scatter (also zero-fills) =================
__global__ void k_out(const float* __restrict__ numer, const unsigned* __restrict__ red,
                      float* __restrict__ out) {
    int idx = blockIdx.x * 256 + threadIdx.x;
    if (idx >= Bg * Nn * Nn) return;
    int b = idx >> 12;
    int rem = idx & 4095;
    int r = rem >> 6, c = rem & 63;
    float v = 0.f;
    if (c > r) {
        int e = b * Ee + (r * (127 - r)) / 2 + (c - r - 1);
        float Sinv = __builtin_amdgcn_rcpf(((const float*)red)[1]);
        v = numer[e] * Sinv;
    }
    out[idx] = v;
}

extern "C" void kernel_launch(void* const* d_in, const int* in_sizes, int n_in,
                              void* d_out, int out_size, void* d_ws, size_t ws_size,
                              hipStream_t stream) {
    const float* topo = (const float*)d_in[0];
    const float* temp = (const float*)d_in[1];
    const float* gu   = (const float*)d_in[2];
    const float* Wg   = (const float*)d_in[3];
    const float* bg   = (const float*)d_in[4];
    const float* Wm   = (const float*)d_in[5];
    const float* bm   = (const float*)d_in[6];
    const float* Wv   = (const float*)d_in[7];
    const float* bv   = (const float*)d_in[8];
    const float* Ww   = (const float*)d_in[9];
    const float* bw   = (const float*)d_in[10];
    float* out = (float*)d_out;

    char* ws = (char*)d_ws;
    size_t off = 0;
    auto carve = [&](size_t bytes) { char* p = ws + off; off = (off + bytes + 255) & ~(size_t)255; return p; };

    // r1 hosts aggb (bf16, 5.2 MB) pre-GEMM1, then S_T[576][8192] f32 (18.9 MB).
    char*   r1    = carve((size_t)SCOLS * MROWS * 4);
    float*  ST    = (float*)r1;
    ushort* aggb  = (ushort*)r1;
    ushort* hb    = (ushort*)carve((size_t)MROWS * Hd * 2);      // 4.19 MB
    ushort* WgbS  = (ushort*)carve((size_t)CVT_N * 2);           // 0.16 MB
    ushort* WcatS = (ushort*)carve((size_t)PACK_N * 2);          // 0.29 MB
    float*  ebias = (float*)carve((size_t)SCOLS * 4);
    float*  numer = (float*)carve((size_t)TOTE * 4);             // 1.03 MB
    unsigned* red = (unsigned*)carve(256);

    const int prep_blks = (CVT_N + PACK_N + SCOLS + 255) / 256;
    k_agg_prep<<<AGG_BLKS + prep_blks, 256, 0, stream>>>(
        topo, temp, Wg, Wm, Wv, Ww, bm, bv, bw, aggb, WgbS, WcatS, ebias, red);
    // GEMM1: hb[8192,256] = relu(aggb[8192,320] @ Wg + bg)
    k_gemm_direct<INF><<<dim3(Hd / 64, MROWS / 64), 256, 0, stream>>>(
        aggb, WgbS, bg, hb, nullptr, Hd, 1, 0);
    // GEMM2: ST[576][8192] = (hb[8192,256] @ Wcat + ebias)^T
    k_gemm_direct<Hd><<<dim3(SCOLS / 64, MROWS / 64), 256, 0, stream>>>(
        hb, WcatS, ebias, nullptr, ST, SCOLS, 0, 1);
    k_edge4<<<Bg * 10, 256, 0, stream>>>(ST, gu, numer, red);
    k_out<<<(Bg * Nn * Nn + 255) / 256, 256, 0, stream>>>(numer, red, out);
}